// Round 3
// baseline (672.115 us; speedup 1.0000x reference)
//
#include <hip/hip_runtime.h>

// MPLayer: y[b,v] += p[r]*x[b,u]; y[b,u] += p[r]*x[b,v]  per edge (u,v), relation r.
// R=64, E=100000, N=1000000, B=4.
//
// R3 strategy: device-scope f32 atomics execute at the memory-side coherence
// point (~20.5G transactions/s wall, measured R1/R2). Instead: 8 private yT
// copies (one per XCD); each workgroup accumulates into copies[xcc_id] with
// WORKGROUP-scope atomics, which stay in the local XCD's L2 (all CUs of an
// XCD share one TCC -> RMW atomic across the whole XCD). Cross-XCD races are
// impossible by construction. Final kernel reduces the 8 copies -> y[4][N].

constexpr int  R_  = 64;
constexpr long E_  = 100000;
constexpr int  N_  = 1000000;
constexpr long RE_ = (long)R_ * E_;     // 6.4M edges
constexpr int  NCOPY = 8;               // one per XCD (m09: XCC_ID in 0..7)

__device__ __forceinline__ int xcc_id() {
    int x;
    asm volatile("s_getreg_b32 %0, hwreg(HW_REG_XCC_ID)" : "=s"(x));
    return x & (NCOPY - 1);
}

__global__ __launch_bounds__(256) void k_transpose_x(const float* __restrict__ x,
                                                     float4* __restrict__ xT) {
    int i = blockIdx.x * blockDim.x + threadIdx.x;
    if (i < N_) {
        float4 v;
        v.x = x[i];
        v.y = x[(long)N_ + i];
        v.z = x[2L * N_ + i];
        v.w = x[3L * N_ + i];
        xT[i] = v;
    }
}

// one thread per (edge, batch component); both directions handled here so the
// edge array is read once. 4 consecutive lanes share one edge -> gathers and
// atomics are 16B-segment-coalesced within the wave.
__global__ __launch_bounds__(256) void k_scatter_xcd(const int2* __restrict__ edges,
                                                     const float* __restrict__ p,
                                                     const float* __restrict__ xT,
                                                     float* __restrict__ copies) {
    float* mine = copies + (size_t)xcc_id() * (4L * N_);
    const long total  = RE_ * 4;              // 25.6M lane-tasks
    const long stride = (long)gridDim.x * blockDim.x;
    for (long t = (long)blockIdx.x * blockDim.x + threadIdx.x; t < total; t += stride) {
        long m = t >> 2;                      // edge id
        int  c = (int)(t & 3);                // batch component
        int2 e = edges[m];
        float w  = p[(int)(m / E_)];
        float xu = xT[4L * e.x + c];
        float xv = xT[4L * e.y + c];
        __hip_atomic_fetch_add(&mine[4L * e.y + c], w * xu,
                               __ATOMIC_RELAXED, __HIP_MEMORY_SCOPE_WORKGROUP);
        __hip_atomic_fetch_add(&mine[4L * e.x + c], w * xv,
                               __ATOMIC_RELAXED, __HIP_MEMORY_SCOPE_WORKGROUP);
    }
}

// sum the 8 XCD-private copies and emit y in [4][N] layout
__global__ __launch_bounds__(256) void k_reduce_copies(const float4* __restrict__ copies,
                                                       float* __restrict__ y) {
    int i = blockIdx.x * blockDim.x + threadIdx.x;
    if (i < N_) {
        float sx = 0.f, sy = 0.f, sz = 0.f, sw = 0.f;
        #pragma unroll
        for (int k = 0; k < NCOPY; ++k) {
            float4 v = copies[(size_t)k * N_ + i];
            sx += v.x; sy += v.y; sz += v.z; sw += v.w;
        }
        y[i]            = sx;
        y[(long)N_ + i] = sy;
        y[2L * N_ + i]  = sz;
        y[3L * N_ + i]  = sw;
    }
}

// ---------- fallback path (R2 structure) if workspace too small ----------
__global__ __launch_bounds__(256) void k_scatter_T2(const int2* __restrict__ edges,
                                                    const float* __restrict__ p,
                                                    const float* __restrict__ xT,
                                                    float* __restrict__ yT) {
    const long total  = RE_ * 2 * 4;
    const long stride = (long)gridDim.x * blockDim.x;
    for (long t = (long)blockIdx.x * blockDim.x + threadIdx.x; t < total; t += stride) {
        long m = t >> 2;
        int  c = (int)(t & 3);
        long mm = (m >= RE_) ? (m - RE_) : m;
        int2 e = edges[mm];
        int s, d;
        if (m >= RE_) { s = e.y; d = e.x; } else { s = e.x; d = e.y; }
        float w   = p[(int)(mm / E_)];
        float val = w * xT[4L * s + c];
        atomicAdd(&yT[4L * d + c], val);
    }
}

__global__ __launch_bounds__(256) void k_transpose_y(const float4* __restrict__ yT,
                                                     float* __restrict__ y) {
    int i = blockIdx.x * blockDim.x + threadIdx.x;
    if (i < N_) {
        float4 v = yT[i];
        y[i]            = v.x;
        y[(long)N_ + i] = v.y;
        y[2L * N_ + i]  = v.z;
        y[3L * N_ + i]  = v.w;
    }
}

__global__ __launch_bounds__(256) void k_scatter_direct(const int2* __restrict__ edges,
                                                        const float* __restrict__ p,
                                                        const float* __restrict__ x,
                                                        float* __restrict__ y) {
    const long stride = (long)gridDim.x * blockDim.x;
    for (long k = (long)blockIdx.x * blockDim.x + threadIdx.x; k < RE_; k += stride) {
        int2 e = edges[k];
        float w = p[(int)(k / E_)];
        #pragma unroll
        for (int b = 0; b < 4; ++b) {
            float xu = x[(long)b * N_ + e.x];
            float xv = x[(long)b * N_ + e.y];
            atomicAdd(&y[(long)b * N_ + e.y], w * xu);
            atomicAdd(&y[(long)b * N_ + e.x], w * xv);
        }
    }
}

extern "C" void kernel_launch(void* const* d_in, const int* in_sizes, int n_in,
                              void* d_out, int out_size, void* d_ws, size_t ws_size,
                              hipStream_t stream) {
    const float* p     = (const float*)d_in[0];
    const int*   edges = (const int*)d_in[1];
    const float* x     = (const float*)d_in[2];
    float*       y     = (float*)d_out;

    const size_t xT_bytes   = (size_t)N_ * 4 * sizeof(float);   // 16 MB
    const size_t copy_bytes = (size_t)NCOPY * xT_bytes;         // 128 MB

    if (ws_size >= xT_bytes + copy_bytes) {
        float4* xT     = (float4*)d_ws;
        float*  copies = (float*)((char*)d_ws + xT_bytes);
        hipMemsetAsync(copies, 0, copy_bytes, stream);
        k_transpose_x<<<(N_ + 255) / 256, 256, 0, stream>>>(x, xT);
        k_scatter_xcd<<<16384, 256, 0, stream>>>((const int2*)edges, p,
                                                 (const float*)xT, copies);
        k_reduce_copies<<<(N_ + 255) / 256, 256, 0, stream>>>((const float4*)copies, y);
    } else if (ws_size >= 2 * xT_bytes) {
        float4* xT = (float4*)d_ws;
        float*  yT = (float*)((char*)d_ws + xT_bytes);
        hipMemsetAsync(yT, 0, xT_bytes, stream);
        k_transpose_x<<<(N_ + 255) / 256, 256, 0, stream>>>(x, xT);
        k_scatter_T2<<<16384, 256, 0, stream>>>((const int2*)edges, p,
                                                (const float*)xT, yT);
        k_transpose_y<<<(N_ + 255) / 256, 256, 0, stream>>>((const float4*)yT, y);
    } else {
        hipMemsetAsync(y, 0, (size_t)out_size * sizeof(float), stream);
        k_scatter_direct<<<8192, 256, 0, stream>>>((const int2*)edges, p, x, y);
    }
}

// Round 4
// 488.765 us; speedup vs baseline: 1.3751x; 1.3751x over previous
//
#include <hip/hip_runtime.h>

// MPLayer: y[b,v] += p[r]*x[b,u]; y[b,u] += p[r]*x[b,v]  per edge (u,v), relation r.
// R=64, E=100000, N=1000000, B=4.
//
// R4: global f32 atomics are a hard memory-side wall (~20.5G trans/s, measured
// R1-R3, scope-independent). Instead, counting-sort the 12.8M directed messages
// by destination bucket (2048 entities), then one block per bucket accumulates
// in LDS (ds_add_f32) and writes each output element once. No memory-side RMW.

constexpr int  R_  = 64;
constexpr long E_  = 100000;
constexpr int  N_  = 1000000;
constexpr long RE_ = (long)R_ * E_;              // 6.4M edges
constexpr long M2_ = 2 * RE_;                    // 12.8M messages
constexpr int  BSH = 11;
constexpr int  BUCKET = 1 << BSH;                // 2048 entities per bucket
constexpr int  NB  = (N_ + BUCKET - 1) >> BSH;   // 489 buckets
constexpr int  EPB = 8192;                       // edges per block (hist/scatter)
constexpr int  HB  = (int)((RE_ + EPB - 1) / EPB); // 782 blocks

// --- transpose x [4][N] -> xT [N][4] ---
__global__ __launch_bounds__(256) void k_transpose_x(const float* __restrict__ x,
                                                     float4* __restrict__ xT) {
    int i = blockIdx.x * blockDim.x + threadIdx.x;
    if (i < N_) {
        float4 v;
        v.x = x[i];
        v.y = x[(long)N_ + i];
        v.z = x[2L * N_ + i];
        v.w = x[3L * N_ + i];
        xT[i] = v;
    }
}

// --- pass 1: per-bucket message histogram (LDS-aggregated) ---
__global__ __launch_bounds__(256) void k_hist(const int2* __restrict__ edges,
                                              int* __restrict__ g_cnt) {
    __shared__ int lcnt[NB];
    for (int t = threadIdx.x; t < NB; t += 256) lcnt[t] = 0;
    __syncthreads();
    long k0 = (long)blockIdx.x * EPB;
    for (int i = threadIdx.x; i < EPB; i += 256) {
        long k = k0 + i;
        if (k < RE_) {
            int2 e = edges[k];
            atomicAdd(&lcnt[e.y >> BSH], 1);   // msg u->v lands at v
            atomicAdd(&lcnt[e.x >> BSH], 1);   // msg v->u lands at u
        }
    }
    __syncthreads();
    for (int t = threadIdx.x; t < NB; t += 256)
        if (lcnt[t]) atomicAdd(&g_cnt[t], lcnt[t]);
}

// --- pass 2: exclusive prefix over 489 bucket counts ---
__global__ __launch_bounds__(512) void k_prefix(const int* __restrict__ g_cnt,
                                                int* __restrict__ g_base,
                                                int* __restrict__ g_tail) {
    __shared__ int lc[NB];
    for (int t = threadIdx.x; t < NB; t += 512) lc[t] = g_cnt[t];
    __syncthreads();
    if (threadIdx.x == 0) {
        int s = 0;
        for (int b = 0; b < NB; ++b) { int c = lc[b]; lc[b] = s; s += c; }
    }
    __syncthreads();
    for (int t = threadIdx.x; t < NB; t += 512) { g_base[t] = lc[t]; g_tail[t] = lc[t]; }
}

// --- pass 3: bin messages into bucket-sorted records {dst|r<<20, src} ---
__global__ __launch_bounds__(256) void k_scatter_bin(const int2* __restrict__ edges,
                                                     int* __restrict__ g_tail,
                                                     uint2* __restrict__ g_rec) {
    __shared__ int lcnt[NB];
    __shared__ int lbase[NB];
    for (int t = threadIdx.x; t < NB; t += 256) lcnt[t] = 0;
    __syncthreads();
    long k0 = (long)blockIdx.x * EPB;
    for (int i = threadIdx.x; i < EPB; i += 256) {
        long k = k0 + i;
        if (k < RE_) {
            int2 e = edges[k];
            atomicAdd(&lcnt[e.y >> BSH], 1);
            atomicAdd(&lcnt[e.x >> BSH], 1);
        }
    }
    __syncthreads();
    for (int t = threadIdx.x; t < NB; t += 256) {
        int c = lcnt[t];
        lbase[t] = c ? atomicAdd(&g_tail[t], c) : 0;
        lcnt[t] = 0;                     // reuse as intra-block cursor
    }
    __syncthreads();
    for (int i = threadIdx.x; i < EPB; i += 256) {
        long k = k0 + i;
        if (k < RE_) {
            int2 e = edges[k];
            unsigned r = (unsigned)((unsigned long)k / (unsigned long)E_);
            int bv = e.y >> BSH;
            int s1 = lbase[bv] + atomicAdd(&lcnt[bv], 1);
            g_rec[s1] = make_uint2((unsigned)e.y | (r << 20), (unsigned)e.x);
            int bu = e.x >> BSH;
            int s2 = lbase[bu] + atomicAdd(&lcnt[bu], 1);
            g_rec[s2] = make_uint2((unsigned)e.x | (r << 20), (unsigned)e.y);
        }
    }
}

// --- pass 4: one block per bucket, LDS accumulate, write y [4][N] once ---
__global__ __launch_bounds__(1024) void k_accum(const uint2* __restrict__ g_rec,
                                                const int* __restrict__ g_base,
                                                const int* __restrict__ g_cnt,
                                                const float* __restrict__ p,
                                                const float4* __restrict__ xT,
                                                float* __restrict__ y) {
    __shared__ float acc[4][BUCKET];     // SoA: 4 adds/msg hit 32 banks
    __shared__ float pl[R_];
    int b = blockIdx.x;
    for (int j = threadIdx.x; j < 4 * BUCKET; j += 1024) ((float*)acc)[j] = 0.f;
    if (threadIdx.x < R_) pl[threadIdx.x] = p[threadIdx.x];
    __syncthreads();
    int s0 = g_base[b], cnt = g_cnt[b];
    int base_e = b << BSH;
    for (int i = threadIdx.x; i < cnt; i += 1024) {
        uint2 rec = g_rec[s0 + i];
        int   dl  = (int)(rec.x & 0xFFFFFu) - base_e;
        float w   = pl[rec.x >> 20];
        float4 xv = xT[rec.y];
        atomicAdd(&acc[0][dl], w * xv.x);
        atomicAdd(&acc[1][dl], w * xv.y);
        atomicAdd(&acc[2][dl], w * xv.z);
        atomicAdd(&acc[3][dl], w * xv.w);
    }
    __syncthreads();
    for (int j = threadIdx.x; j < BUCKET; j += 1024) {
        int i = base_e + j;
        if (i < N_) {
            y[i]            = acc[0][j];
            y[(long)N_ + i] = acc[1][j];
            y[2L * N_ + i]  = acc[2][j];
            y[3L * N_ + i]  = acc[3][j];
        }
    }
}

// ---------- fallbacks (R2 structure / direct) ----------
__global__ __launch_bounds__(256) void k_scatter_T2(const int2* __restrict__ edges,
                                                    const float* __restrict__ p,
                                                    const float* __restrict__ xT,
                                                    float* __restrict__ yT) {
    const long total  = M2_ * 4;
    const long stride = (long)gridDim.x * blockDim.x;
    for (long t = (long)blockIdx.x * blockDim.x + threadIdx.x; t < total; t += stride) {
        long m = t >> 2;
        int  c = (int)(t & 3);
        long mm = (m >= RE_) ? (m - RE_) : m;
        int2 e = edges[mm];
        int s, d;
        if (m >= RE_) { s = e.y; d = e.x; } else { s = e.x; d = e.y; }
        float w   = p[(int)(mm / E_)];
        float val = w * xT[4L * s + c];
        atomicAdd(&yT[4L * d + c], val);
    }
}

__global__ __launch_bounds__(256) void k_transpose_y(const float4* __restrict__ yT,
                                                     float* __restrict__ y) {
    int i = blockIdx.x * blockDim.x + threadIdx.x;
    if (i < N_) {
        float4 v = yT[i];
        y[i]            = v.x;
        y[(long)N_ + i] = v.y;
        y[2L * N_ + i]  = v.z;
        y[3L * N_ + i]  = v.w;
    }
}

__global__ __launch_bounds__(256) void k_scatter_direct(const int2* __restrict__ edges,
                                                        const float* __restrict__ p,
                                                        const float* __restrict__ x,
                                                        float* __restrict__ y) {
    const long stride = (long)gridDim.x * blockDim.x;
    for (long k = (long)blockIdx.x * blockDim.x + threadIdx.x; k < RE_; k += stride) {
        int2 e = edges[k];
        float w = p[(int)(k / E_)];
        #pragma unroll
        for (int b = 0; b < 4; ++b) {
            float xu = x[(long)b * N_ + e.x];
            float xv = x[(long)b * N_ + e.y];
            atomicAdd(&y[(long)b * N_ + e.y], w * xu);
            atomicAdd(&y[(long)b * N_ + e.x], w * xv);
        }
    }
}

extern "C" void kernel_launch(void* const* d_in, const int* in_sizes, int n_in,
                              void* d_out, int out_size, void* d_ws, size_t ws_size,
                              hipStream_t stream) {
    const float* p     = (const float*)d_in[0];
    const int*   edges = (const int*)d_in[1];
    const float* x     = (const float*)d_in[2];
    float*       y     = (float*)d_out;

    const size_t xT_bytes  = (size_t)N_ * 4 * sizeof(float);    // 16.0 MB
    const size_t rec_bytes = (size_t)M2_ * sizeof(uint2);       // 102.4 MB
    const size_t cnt_bytes = (size_t)NB * sizeof(int);          // ~2 KB each

    if (ws_size >= xT_bytes + rec_bytes + 3 * cnt_bytes) {
        char*   ws     = (char*)d_ws;
        float4* xT     = (float4*)ws;                       ws += xT_bytes;
        uint2*  g_rec  = (uint2*)ws;                        ws += rec_bytes;
        int*    g_cnt  = (int*)ws;                          ws += cnt_bytes;
        int*    g_base = (int*)ws;                          ws += cnt_bytes;
        int*    g_tail = (int*)ws;

        hipMemsetAsync(g_cnt, 0, cnt_bytes, stream);
        k_transpose_x<<<(N_ + 255) / 256, 256, 0, stream>>>(x, xT);
        k_hist<<<HB, 256, 0, stream>>>((const int2*)edges, g_cnt);
        k_prefix<<<1, 512, 0, stream>>>(g_cnt, g_base, g_tail);
        k_scatter_bin<<<HB, 256, 0, stream>>>((const int2*)edges, g_tail, g_rec);
        k_accum<<<NB, 1024, 0, stream>>>((const uint2*)g_rec, g_base, g_cnt, p,
                                         (const float4*)xT, y);
    } else if (ws_size >= 2 * xT_bytes) {
        float4* xT = (float4*)d_ws;
        float*  yT = (float*)((char*)d_ws + xT_bytes);
        hipMemsetAsync(yT, 0, xT_bytes, stream);
        k_transpose_x<<<(N_ + 255) / 256, 256, 0, stream>>>(x, xT);
        k_scatter_T2<<<16384, 256, 0, stream>>>((const int2*)edges, p,
                                                (const float*)xT, yT);
        k_transpose_y<<<(N_ + 255) / 256, 256, 0, stream>>>((const float4*)yT, y);
    } else {
        hipMemsetAsync(y, 0, (size_t)out_size * sizeof(float), stream);
        k_scatter_direct<<<8192, 256, 0, stream>>>((const int2*)edges, p, x, y);
    }
}